// Round 6
// baseline (2154.617 us; speedup 1.0000x reference)
//
#include <hip/hip_runtime.h>

#define B_TOT   8192
#define T_STEPS 256
#define D_INP   17
#define ROWS    8
#define OUT0 ((long)B_TOT * T_STEPS * D_INP)

__device__ __forceinline__ float fsig(float x) {
    float t = __builtin_amdgcn_exp2f(-1.4426950408889634f * x);
    return __builtin_amdgcn_rcpf(1.0f + t);
}
__device__ __forceinline__ float ftanh(float x) {
    float t = __builtin_amdgcn_exp2f(-2.8853900817779268f * x);
    return 2.0f * __builtin_amdgcn_rcpf(1.0f + t) - 1.0f;
}

__global__ __launch_bounds__(256)
void lstm_ae_valu(const float* __restrict__ x,
                  const float* __restrict__ wih_e,
                  const float* __restrict__ whh_e,
                  const float* __restrict__ bih_e,
                  const float* __restrict__ bhh_e,
                  const float* __restrict__ w_encfc,
                  const float* __restrict__ b_encfc,
                  const float* __restrict__ w_decfc,
                  const float* __restrict__ b_decfc,
                  const float* __restrict__ wih_d,
                  const float* __restrict__ whh_d,
                  const float* __restrict__ bih_d,
                  const float* __restrict__ bhh_d,
                  float* __restrict__ out)
{
    __shared__ float WEih[17][128];   // [k][gate_row]
    __shared__ float WEhh[32][128];
    __shared__ float WDih[32][68];
    __shared__ float WDhh[17][68];
    __shared__ float be[128], bd[68];
    __shared__ float WEfc[256], WDfc[256];
    __shared__ float bEfc[8], bDfc[32];
    __shared__ float hb[ROWS][33];
    __shared__ float db[ROWS][33];
    __shared__ float zb[ROWS][8];

    const int tid = threadIdx.x;

    for (int i = tid; i < 128*17; i += 256) { int g = i / 17, k = i % 17; WEih[k][g] = wih_e[i]; }
    for (int i = tid; i < 128*32; i += 256) { int g = i >> 5, k = i & 31; WEhh[k][g] = whh_e[i]; }
    for (int i = tid; i < 68*32;  i += 256) { int g = i >> 5, k = i & 31; WDih[k][g] = wih_d[i]; }
    for (int i = tid; i < 68*17;  i += 256) { int g = i / 17, k = i % 17; WDhh[k][g] = whh_d[i]; }
    if (tid < 128) be[tid] = bih_e[tid] + bhh_e[tid];
    if (tid < 68)  bd[tid] = bih_d[tid] + bhh_d[tid];
    WEfc[tid] = w_encfc[tid & 255];
    WDfc[tid] = w_decfc[tid & 255];
    if (tid < 8)   bEfc[tid] = b_encfc[tid];
    if (tid < 32)  bDfc[tid] = b_decfc[tid];

    const int r = tid >> 5;          // batch row within block
    const int j = tid & 31;          // hidden index
    const long b = (long)blockIdx.x * ROWS + r;

    hb[r][j] = 0.f;
    __syncthreads();

    const float* xb = x + b * (T_STEPS * D_INP);
    float c = 0.f;

    // ---------------- encoder ----------------
    for (int t = 0; t < T_STEPS; ++t) {
        float ai = be[j], af = be[32+j], ag = be[64+j], ao = be[96+j];
        const float* xt = xb + t * D_INP;
#pragma unroll
        for (int k = 0; k < 17; ++k) {
            const float xv = xt[k];
            ai += xv * WEih[k][j];
            af += xv * WEih[k][32+j];
            ag += xv * WEih[k][64+j];
            ao += xv * WEih[k][96+j];
        }
#pragma unroll
        for (int k = 0; k < 32; ++k) {
            const float hv = hb[r][k];
            ai += hv * WEhh[k][j];
            af += hv * WEhh[k][32+j];
            ag += hv * WEhh[k][64+j];
            ao += hv * WEhh[k][96+j];
        }
        const float ii = fsig(ai), ff = fsig(af), gg = ftanh(ag), oo = fsig(ao);
        c = ff * c + ii * gg;
        const float hn = oo * ftanh(c);
        __syncthreads();
        hb[r][j] = hn;
        __syncthreads();
    }

    // ---------------- enc_fc ----------------
    if (j < 8) {
        float s = bEfc[j];
#pragma unroll
        for (int k = 0; k < 32; ++k) s += hb[r][k] * WEfc[j*32 + k];
        zb[r][j] = s;
        out[OUT0 + b*8 + j] = s;
    }
    __syncthreads();

    // ---------------- dec_fc ----------------
    {
        float s = bDfc[j];
#pragma unroll
        for (int p = 0; p < 8; ++p) s += zb[r][p] * WDfc[j*8 + p];
        db[r][j] = s;
    }
    hb[r][j] = 0.f;
    __syncthreads();

    // ---------------- decoder xg precompute (constant over t) ----------------
    float xgi = 0.f, xgf = 0.f, xgg = 0.f, xgo = 0.f;
    if (j < 17) {
        xgi = bd[j]; xgf = bd[17+j]; xgg = bd[34+j]; xgo = bd[51+j];
#pragma unroll
        for (int k = 0; k < 32; ++k) {
            const float dv = db[r][k];
            xgi += dv * WDih[k][j];
            xgf += dv * WDih[k][17+j];
            xgg += dv * WDih[k][34+j];
            xgo += dv * WDih[k][51+j];
        }
    }

    float cd = 0.f;
    float* ob = out + b * (T_STEPS * D_INP);

    // ---------------- decoder ----------------
    for (int t = 0; t < T_STEPS; ++t) {
        float h = 0.f;
        if (j < 17) {
            float ai = xgi, af = xgf, ag = xgg, ao = xgo;
#pragma unroll
            for (int k = 0; k < 17; ++k) {
                const float hv = hb[r][k];
                ai += hv * WDhh[k][j];
                af += hv * WDhh[k][17+j];
                ag += hv * WDhh[k][34+j];
                ao += hv * WDhh[k][51+j];
            }
            const float ii = fsig(ai), ff = fsig(af), gg2 = ftanh(ag), oo = fsig(ao);
            cd = ff * cd + ii * gg2;
            h = oo * ftanh(cd);
        }
        __syncthreads();
        if (j < 17) {
            hb[r][j] = h;
            ob[t * D_INP + j] = h;
        }
        __syncthreads();
    }
}

extern "C" void kernel_launch(void* const* d_in, const int* in_sizes, int n_in,
                              void* d_out, int out_size, void* d_ws, size_t ws_size,
                              hipStream_t stream) {
    (void)in_sizes; (void)n_in; (void)d_ws; (void)ws_size; (void)out_size;
    dim3 grid(B_TOT / ROWS);
    dim3 block(256);
    hipLaunchKernelGGL(lstm_ae_valu, grid, block, 0, stream,
        (const float*)d_in[0],
        (const float*)d_in[1],
        (const float*)d_in[2],
        (const float*)d_in[3],
        (const float*)d_in[4],
        (const float*)d_in[5],
        (const float*)d_in[6],
        (const float*)d_in[7],
        (const float*)d_in[8],
        (const float*)d_in[9],
        (const float*)d_in[10],
        (const float*)d_in[11],
        (const float*)d_in[12],
        (float*)d_out);
}

// Round 7
// 615.496 us; speedup vs baseline: 3.5006x; 3.5006x over previous
//
#include <hip/hip_runtime.h>

typedef float f32x4 __attribute__((ext_vector_type(4)));
typedef short short8 __attribute__((ext_vector_type(8)));

#define B_TOT   8192
#define T_STEPS 256
#define D_INP   17
#define OUT0 ((long)B_TOT * T_STEPS * D_INP)

__device__ __forceinline__ float bf2f(unsigned short u) {
    union { unsigned int i; float f; } v; v.i = ((unsigned int)u) << 16; return v.f;
}
__device__ __forceinline__ unsigned short f2bf(float x) {
    union { float f; unsigned int i; } v; v.f = x;
    unsigned int r = (v.i + 0x7fffu + ((v.i >> 16) & 1u)) >> 16;
    return (unsigned short)r;
}
__device__ __forceinline__ short f2bfs(float x) { return (short)f2bf(x); }

__device__ __forceinline__ float fsig(float x) {
    float t = __builtin_amdgcn_exp2f(-1.4426950408889634f * x);
    return __builtin_amdgcn_rcpf(1.0f + t);
}
__device__ __forceinline__ float ftanh(float x) {
    float t = __builtin_amdgcn_exp2f(-2.8853900817779268f * x);
    return 2.0f * __builtin_amdgcn_rcpf(1.0f + t) - 1.0f;
}

union W4 { uint4 u; short8 s; };

__global__ __launch_bounds__(64, 1)
void lstm_ae_mfma(const float* __restrict__ x,
                  const float* __restrict__ wih_e,
                  const float* __restrict__ whh_e,
                  const float* __restrict__ bih_e,
                  const float* __restrict__ bhh_e,
                  const float* __restrict__ w_encfc,
                  const float* __restrict__ b_encfc,
                  const float* __restrict__ w_decfc,
                  const float* __restrict__ b_decfc,
                  const float* __restrict__ wih_d,
                  const float* __restrict__ whh_d,
                  const float* __restrict__ bih_d,
                  const float* __restrict__ bhh_d,
                  float* __restrict__ out)
{
    const int lane = threadIdx.x;
    const int n    = lane & 15;   // batch row within tile (MFMA N col / C-D col)
    const int G    = lane >> 4;   // k-group / C-D row group
    const int row0 = blockIdx.x * 16;

    __shared__ unsigned int hbh[16][20];   // hi bf16 h exchange (word-typed)
    __shared__ unsigned int hbm[16][20];   // mid bf16 h exchange
    __shared__ float hfin[16][32];
    __shared__ float zbuf[16][8];

    // ---------------- encoder fragments ----------------
    // x-path: plain bf16 weights. h-path: hi+mid split (recurrent error compounds).
    short8 AihH[8], AwhH[8], AwhM[8];
    f32x4  bias_e[8];
#pragma unroll
    for (int m = 0; m < 8; ++m) {
        const int grow = 16*m + n;            // gate row 0..127
#pragma unroll
        for (int e = 0; e < 8; ++e) {
            const int k = 8*G + e;
            const float wv = whh_e[grow*32 + k];
            const short hi = f2bfs(wv);
            AwhH[m][e] = hi;
            AwhM[m][e] = f2bfs(wv - bf2f((unsigned short)hi));
            AihH[m][e] = (k < D_INP) ? f2bfs(wih_e[grow*D_INP + k]) : (short)0;
        }
#pragma unroll
        for (int r = 0; r < 4; ++r) {
            const int g = 16*m + 4*G + r;
            bias_e[m][r] = bih_e[g] + bhh_e[g];
        }
    }

    float c[8], h[8];
#pragma unroll
    for (int s = 0; s < 8; ++s) { c[s] = 0.f; h[s] = 0.f; }

    short8 bhH, bhM;
#pragma unroll
    for (int e = 0; e < 8; ++e) { bhH[e] = 0; bhM[e] = 0; }

    const long xrow = (long)(row0 + n) * (T_STEPS * D_INP);

    float xv[8];
#pragma unroll
    for (int e = 0; e < 8; ++e) {
        const int k = 8*G + e;
        xv[e] = (k < D_INP) ? x[xrow + k] : 0.f;
    }

    // ---------------- encoder loop ----------------
    for (int t = 0; t < T_STEPS; ++t) {
        const int tn = (t+1 < T_STEPS) ? (t+1) : t;
        float xn[8];
#pragma unroll
        for (int e = 0; e < 8; ++e) {
            const int k = 8*G + e;
            xn[e] = (k < D_INP) ? x[xrow + (long)tn*D_INP + k] : 0.f;
        }

        short8 bx;
#pragma unroll
        for (int e = 0; e < 8; ++e) bx[e] = f2bfs(xv[e]);

        f32x4 acc[8];
#pragma unroll
        for (int m = 0; m < 8; ++m) acc[m] = bias_e[m];
#pragma unroll
        for (int m = 0; m < 8; ++m)
            acc[m] = __builtin_amdgcn_mfma_f32_16x16x32_bf16(AihH[m], bx, acc[m], 0, 0, 0);
#pragma unroll
        for (int m = 0; m < 8; ++m)
            acc[m] = __builtin_amdgcn_mfma_f32_16x16x32_bf16(AwhH[m], bhH, acc[m], 0, 0, 0);
#pragma unroll
        for (int m = 0; m < 8; ++m)
            acc[m] = __builtin_amdgcn_mfma_f32_16x16x32_bf16(AwhM[m], bhH, acc[m], 0, 0, 0);
#pragma unroll
        for (int m = 0; m < 8; ++m)
            acc[m] = __builtin_amdgcn_mfma_f32_16x16x32_bf16(AwhH[m], bhM, acc[m], 0, 0, 0);

        unsigned short huH[8], huM[8];
#pragma unroll
        for (int half = 0; half < 2; ++half) {
#pragma unroll
            for (int r = 0; r < 4; ++r) {
                const int s = 4*half + r;
                const float gi = acc[0+half][r];
                const float gf = acc[2+half][r];
                const float gg = acc[4+half][r];
                const float go = acc[6+half][r];
                const float cn = fsig(gf)*c[s] + fsig(gi)*ftanh(gg);
                c[s] = cn;
                const float hn = fsig(go)*ftanh(cn);
                h[s] = hn;
                const unsigned short hh = f2bf(hn);
                huH[s] = hh;
                huM[s] = f2bf(hn - bf2f(hh));
            }
        }

        *(uint2*)&hbh[n][2*G]     = make_uint2((unsigned)huH[0] | ((unsigned)huH[1]<<16),
                                               (unsigned)huH[2] | ((unsigned)huH[3]<<16));
        *(uint2*)&hbh[n][8 + 2*G] = make_uint2((unsigned)huH[4] | ((unsigned)huH[5]<<16),
                                               (unsigned)huH[6] | ((unsigned)huH[7]<<16));
        *(uint2*)&hbm[n][2*G]     = make_uint2((unsigned)huM[0] | ((unsigned)huM[1]<<16),
                                               (unsigned)huM[2] | ((unsigned)huM[3]<<16));
        *(uint2*)&hbm[n][8 + 2*G] = make_uint2((unsigned)huM[4] | ((unsigned)huM[5]<<16),
                                               (unsigned)huM[6] | ((unsigned)huM[7]<<16));
        __syncthreads();
        { W4 w1; w1.u = *(const uint4*)&hbh[n][4*G]; bhH = w1.s; }
        { W4 w2; w2.u = *(const uint4*)&hbm[n][4*G]; bhM = w2.s; }
        __syncthreads();

#pragma unroll
        for (int e = 0; e < 8; ++e) xv[e] = xn[e];
    }

    // ---------------- enc_fc -> z -> dec_fc ----------------
#pragma unroll
    for (int r = 0; r < 4; ++r) {
        hfin[n][4*G + r]      = h[r];
        hfin[n][16 + 4*G + r] = h[4+r];
    }
    __syncthreads();

#pragma unroll
    for (int ti = 0; ti < 2; ++ti) {
        const int tk = lane*2 + ti;
        const int nn = tk >> 3;
        const int p  = tk & 7;
        float s = b_encfc[p];
        for (int j = 0; j < 32; ++j)
            s += hfin[nn][j] * w_encfc[p*32 + j];
        out[OUT0 + (long)(row0+nn)*8 + p] = s;
        zbuf[nn][p] = s;
    }
    __syncthreads();

    {
        const int nn = lane >> 2;
        const int qb = (lane & 3) * 8;
        unsigned short dH[8], dM[8];
#pragma unroll
        for (int s2 = 0; s2 < 8; ++s2) {
            const int q = qb + s2;
            float v = b_decfc[q];
#pragma unroll
            for (int p = 0; p < 8; ++p)
                v += zbuf[nn][p] * w_decfc[q*8 + p];
            const unsigned short hh = f2bf(v);
            dH[s2] = hh;
            dM[s2] = f2bf(v - bf2f(hh));
        }
        *(uint4*)&hbh[nn][4*(lane & 3)] = make_uint4(
            (unsigned)dH[0] | ((unsigned)dH[1]<<16), (unsigned)dH[2] | ((unsigned)dH[3]<<16),
            (unsigned)dH[4] | ((unsigned)dH[5]<<16), (unsigned)dH[6] | ((unsigned)dH[7]<<16));
        *(uint4*)&hbm[nn][4*(lane & 3)] = make_uint4(
            (unsigned)dM[0] | ((unsigned)dM[1]<<16), (unsigned)dM[2] | ((unsigned)dM[3]<<16),
            (unsigned)dM[4] | ((unsigned)dM[5]<<16), (unsigned)dM[6] | ((unsigned)dM[7]<<16));
    }
    __syncthreads();
    short8 bdvH, bdvM;
    { W4 w1; w1.u = *(const uint4*)&hbh[n][4*G]; bdvH = w1.s; }
    { W4 w2; w2.u = *(const uint4*)&hbm[n][4*G]; bdvM = w2.s; }
    __syncthreads();

    // ---------------- decoder fragments (hidden 17 padded to 32) ----------------
    short8 AwhDH[8], AwhDM[8];
    f32x4  accd[8];
    {
        short8 AihDH[8], AihDM[8];
#pragma unroll
        for (int m = 0; m < 8; ++m) {
            const int gp = 16*m + n;        // padded gate row 0..127
            const int Ty = gp >> 5;
            const int jp = gp & 31;
            const bool rv = (jp < 17);
            const int grow = Ty*17 + jp;
#pragma unroll
            for (int e = 0; e < 8; ++e) {
                const int k = 8*G + e;
                const float iv = rv ? wih_d[grow*32 + k] : 0.f;
                const float wv = (rv && k < 17) ? whh_d[grow*17 + k] : 0.f;
                const short hi = f2bfs(iv);
                AihDH[m][e] = hi;
                AihDM[m][e] = f2bfs(iv - bf2f((unsigned short)hi));
                const short hi2 = f2bfs(wv);
                AwhDH[m][e] = hi2;
                AwhDM[m][e] = f2bfs(wv - bf2f((unsigned short)hi2));
            }
#pragma unroll
            for (int r = 0; r < 4; ++r) {
                const int gq = 16*m + 4*G + r;
                const int Tq = gq >> 5;
                const int jq = gq & 31;
                accd[m][r] = (jq < 17) ? (bih_d[Tq*17+jq] + bhh_d[Tq*17+jq]) : 0.f;
            }
        }
#pragma unroll
        for (int m = 0; m < 8; ++m)
            accd[m] = __builtin_amdgcn_mfma_f32_16x16x32_bf16(AihDH[m], bdvH, accd[m], 0, 0, 0);
#pragma unroll
        for (int m = 0; m < 8; ++m)
            accd[m] = __builtin_amdgcn_mfma_f32_16x16x32_bf16(AihDM[m], bdvH, accd[m], 0, 0, 0);
#pragma unroll
        for (int m = 0; m < 8; ++m)
            accd[m] = __builtin_amdgcn_mfma_f32_16x16x32_bf16(AihDH[m], bdvM, accd[m], 0, 0, 0);
    }

    float cd[8];
#pragma unroll
    for (int s = 0; s < 8; ++s) cd[s] = 0.f;
    short8 bhdH, bhdM;
#pragma unroll
    for (int e = 0; e < 8; ++e) { bhdH[e] = 0; bhdM[e] = 0; }

    const long orow = (long)(row0 + n) * (T_STEPS * D_INP);

    // ---------------- decoder loop ----------------
    for (int t = 0; t < T_STEPS; ++t) {
        f32x4 acc[8];
#pragma unroll
        for (int m = 0; m < 8; ++m) acc[m] = accd[m];
#pragma unroll
        for (int m = 0; m < 8; ++m)
            acc[m] = __builtin_amdgcn_mfma_f32_16x16x32_bf16(AwhDH[m], bhdH, acc[m], 0, 0, 0);
#pragma unroll
        for (int m = 0; m < 8; ++m)
            acc[m] = __builtin_amdgcn_mfma_f32_16x16x32_bf16(AwhDM[m], bhdH, acc[m], 0, 0, 0);
#pragma unroll
        for (int m = 0; m < 8; ++m)
            acc[m] = __builtin_amdgcn_mfma_f32_16x16x32_bf16(AwhDH[m], bhdM, acc[m], 0, 0, 0);

        float hval[8];
        unsigned short huH[8], huM[8];
#pragma unroll
        for (int half = 0; half < 2; ++half) {
#pragma unroll
            for (int r = 0; r < 4; ++r) {
                const int s = 4*half + r;
                const float gi = acc[0+half][r];
                const float gf = acc[2+half][r];
                const float gg = acc[4+half][r];
                const float go = acc[6+half][r];
                const float cn = fsig(gf)*cd[s] + fsig(gi)*ftanh(gg);
                cd[s] = cn;
                const float hn = fsig(go)*ftanh(cn);
                hval[s] = hn;
                const unsigned short hh = f2bf(hn);
                huH[s] = hh;
                huM[s] = f2bf(hn - bf2f(hh));
            }
        }

        *(uint2*)&hbh[n][2*G]     = make_uint2((unsigned)huH[0] | ((unsigned)huH[1]<<16),
                                               (unsigned)huH[2] | ((unsigned)huH[3]<<16));
        *(uint2*)&hbh[n][8 + 2*G] = make_uint2((unsigned)huH[4] | ((unsigned)huH[5]<<16),
                                               (unsigned)huH[6] | ((unsigned)huH[7]<<16));
        *(uint2*)&hbm[n][2*G]     = make_uint2((unsigned)huM[0] | ((unsigned)huM[1]<<16),
                                               (unsigned)huM[2] | ((unsigned)huM[3]<<16));
        *(uint2*)&hbm[n][8 + 2*G] = make_uint2((unsigned)huM[4] | ((unsigned)huM[5]<<16),
                                               (unsigned)huM[6] | ((unsigned)huM[7]<<16));
        __syncthreads();
        { W4 w1; w1.u = *(const uint4*)&hbh[n][4*G]; bhdH = w1.s; }
        { W4 w2; w2.u = *(const uint4*)&hbm[n][4*G]; bhdM = w2.s; }
        __syncthreads();

        const long ob = orow + (long)t*D_INP;
#pragma unroll
        for (int r = 0; r < 4; ++r)
            out[ob + 4*G + r] = hval[r];
        if (G == 0)
            out[ob + 16] = hval[4];
    }
}

extern "C" void kernel_launch(void* const* d_in, const int* in_sizes, int n_in,
                              void* d_out, int out_size, void* d_ws, size_t ws_size,
                              hipStream_t stream) {
    (void)in_sizes; (void)n_in; (void)d_ws; (void)ws_size; (void)out_size;
    dim3 grid(B_TOT / 16);
    dim3 block(64);
    hipLaunchKernelGGL(lstm_ae_mfma, grid, block, 0, stream,
        (const float*)d_in[0],
        (const float*)d_in[1],
        (const float*)d_in[2],
        (const float*)d_in[3],
        (const float*)d_in[4],
        (const float*)d_in[5],
        (const float*)d_in[6],
        (const float*)d_in[7],
        (const float*)d_in[8],
        (const float*)d_in[9],
        (const float*)d_in[10],
        (const float*)d_in[11],
        (const float*)d_in[12],
        (float*)d_out);
}

// Round 8
// 536.961 us; speedup vs baseline: 4.0126x; 1.1463x over previous
//
#include <hip/hip_runtime.h>

typedef float f32x4 __attribute__((ext_vector_type(4)));
typedef short short8 __attribute__((ext_vector_type(8)));

#define B_TOT   8192
#define T_STEPS 256
#define D_INP   17
#define OUT0 ((long)B_TOT * T_STEPS * D_INP)

__device__ __forceinline__ float bf2f(unsigned short u) {
    union { unsigned int i; float f; } v; v.i = ((unsigned int)u) << 16; return v.f;
}
__device__ __forceinline__ unsigned short f2bf(float x) {
    union { float f; unsigned int i; } v; v.f = x;
    unsigned int r = (v.i + 0x7fffu + ((v.i >> 16) & 1u)) >> 16;
    return (unsigned short)r;
}
__device__ __forceinline__ short f2bfs(float x) { return (short)f2bf(x); }

__device__ __forceinline__ float fsig(float x) {
    float t = __builtin_amdgcn_exp2f(-1.4426950408889634f * x);
    return __builtin_amdgcn_rcpf(1.0f + t);
}
__device__ __forceinline__ float ftanh(float x) {
    float t = __builtin_amdgcn_exp2f(-2.8853900817779268f * x);
    return 2.0f * __builtin_amdgcn_rcpf(1.0f + t) - 1.0f;
}

union W4 { uint4 u; short8 s; };

// 2 waves per 16-row batch tile; wave w owns hidden units [16w, 16w+16).
__global__ __launch_bounds__(128, 1)
void lstm_ae_mfma2(const float* __restrict__ x,
                   const float* __restrict__ wih_e,
                   const float* __restrict__ whh_e,
                   const float* __restrict__ bih_e,
                   const float* __restrict__ bhh_e,
                   const float* __restrict__ w_encfc,
                   const float* __restrict__ b_encfc,
                   const float* __restrict__ w_decfc,
                   const float* __restrict__ b_decfc,
                   const float* __restrict__ wih_d,
                   const float* __restrict__ whh_d,
                   const float* __restrict__ bih_d,
                   const float* __restrict__ bhh_d,
                   float* __restrict__ out)
{
    const int tid  = threadIdx.x;
    const int w    = tid >> 6;     // wave id: unit half
    const int lane = tid & 63;
    const int n    = lane & 15;    // batch row within tile (C/D col)
    const int G    = lane >> 4;    // k-group / C/D row group
    const int row0 = blockIdx.x * 16;

    __shared__ unsigned int hbh[16][20];   // hi bf16 h exchange
    __shared__ unsigned int hbm[16][20];   // mid bf16 h exchange
    __shared__ float hfin[16][33];
    __shared__ float zbuf[16][8];

    // ---------------- encoder fragments (gate q = i,f,g,o) ----------------
    short8 AihH[4], AwhH[4], AwhM[4];
    f32x4  biasE[4];
#pragma unroll
    for (int q = 0; q < 4; ++q) {
        const int grow = 32*q + 16*w + n;       // gate row
#pragma unroll
        for (int e = 0; e < 8; ++e) {
            const int k = 8*G + e;
            const float wv = whh_e[grow*32 + k];
            const short hi = f2bfs(wv);
            AwhH[q][e] = hi;
            AwhM[q][e] = f2bfs(wv - bf2f((unsigned short)hi));
            AihH[q][e] = (k < D_INP) ? f2bfs(wih_e[grow*D_INP + k]) : (short)0;
        }
#pragma unroll
        for (int r = 0; r < 4; ++r) {
            const int g = 32*q + 16*w + 4*G + r;
            biasE[q][r] = bih_e[g] + bhh_e[g];
        }
    }

    float c[4], h[4];
#pragma unroll
    for (int s = 0; s < 4; ++s) { c[s] = 0.f; h[s] = 0.f; }

    short8 bhH, bhM;
#pragma unroll
    for (int e = 0; e < 8; ++e) { bhH[e] = 0; bhM[e] = 0; }

    const long xrow = (long)(row0 + n) * (T_STEPS * D_INP);

    float xv[8];
#pragma unroll
    for (int e = 0; e < 8; ++e) {
        const int k = 8*G + e;
        xv[e] = (k < D_INP) ? x[xrow + k] : 0.f;
    }

    // ---------------- encoder loop ----------------
    for (int t = 0; t < T_STEPS; ++t) {
        const int tn = (t+1 < T_STEPS) ? (t+1) : t;
        float xn[8];
#pragma unroll
        for (int e = 0; e < 8; ++e) {
            const int k = 8*G + e;
            xn[e] = (k < D_INP) ? x[xrow + (long)tn*D_INP + k] : 0.f;
        }

        short8 bx;
#pragma unroll
        for (int e = 0; e < 8; ++e) bx[e] = f2bfs(xv[e]);

        f32x4 a[4];
#pragma unroll
        for (int q = 0; q < 4; ++q) a[q] = biasE[q];
#pragma unroll
        for (int q = 0; q < 4; ++q)
            a[q] = __builtin_amdgcn_mfma_f32_16x16x32_bf16(AihH[q], bx, a[q], 0, 0, 0);
#pragma unroll
        for (int q = 0; q < 4; ++q)
            a[q] = __builtin_amdgcn_mfma_f32_16x16x32_bf16(AwhH[q], bhH, a[q], 0, 0, 0);
#pragma unroll
        for (int q = 0; q < 4; ++q)
            a[q] = __builtin_amdgcn_mfma_f32_16x16x32_bf16(AwhM[q], bhH, a[q], 0, 0, 0);
#pragma unroll
        for (int q = 0; q < 4; ++q)
            a[q] = __builtin_amdgcn_mfma_f32_16x16x32_bf16(AwhH[q], bhM, a[q], 0, 0, 0);

        unsigned short huH[4], huM[4];
#pragma unroll
        for (int r = 0; r < 4; ++r) {
            const float cn = fsig(a[1][r])*c[r] + fsig(a[0][r])*ftanh(a[2][r]);
            c[r] = cn;
            const float hn = fsig(a[3][r])*ftanh(cn);
            h[r] = hn;
            huH[r] = f2bf(hn);
            huM[r] = f2bf(hn - bf2f(huH[r]));
        }

        *(uint2*)&hbh[n][8*w + 2*G] = make_uint2((unsigned)huH[0] | ((unsigned)huH[1]<<16),
                                                 (unsigned)huH[2] | ((unsigned)huH[3]<<16));
        *(uint2*)&hbm[n][8*w + 2*G] = make_uint2((unsigned)huM[0] | ((unsigned)huM[1]<<16),
                                                 (unsigned)huM[2] | ((unsigned)huM[3]<<16));
        __syncthreads();
        { W4 w1; w1.u = *(const uint4*)&hbh[n][4*G]; bhH = w1.s; }
        { W4 w2; w2.u = *(const uint4*)&hbm[n][4*G]; bhM = w2.s; }
        __syncthreads();

#pragma unroll
        for (int e = 0; e < 8; ++e) xv[e] = xn[e];
    }

    // ---------------- enc_fc -> z -> dec_fc ----------------
#pragma unroll
    for (int r = 0; r < 4; ++r)
        hfin[n][16*w + 4*G + r] = h[r];
    __syncthreads();

    {   // one (row nn, z-dim p) per thread: 16*8 = 128
        const int nn = tid >> 3;
        const int p  = tid & 7;
        float s = b_encfc[p];
#pragma unroll
        for (int j = 0; j < 32; ++j)
            s += hfin[nn][j] * w_encfc[p*32 + j];
        out[OUT0 + (long)(row0+nn)*8 + p] = s;
        zbuf[nn][p] = s;
    }
    __syncthreads();

    // dec_in (16 rows x 32 dims): each thread computes a q-pair, packs one word
#pragma unroll
    for (int it = 0; it < 2; ++it) {
        const int i  = tid + 128*it;       // word index 0..255
        const int nn = i >> 4;
        const int wq = i & 15;
        unsigned short vh[2], vm[2];
#pragma unroll
        for (int half = 0; half < 2; ++half) {
            const int q = 2*wq + half;
            float v = b_decfc[q];
#pragma unroll
            for (int p = 0; p < 8; ++p)
                v += zbuf[nn][p] * w_decfc[q*8 + p];
            vh[half] = f2bf(v);
            vm[half] = f2bf(v - bf2f(vh[half]));
        }
        hbh[nn][wq] = (unsigned)vh[0] | ((unsigned)vh[1] << 16);
        hbm[nn][wq] = (unsigned)vm[0] | ((unsigned)vm[1] << 16);
    }
    __syncthreads();
    short8 bdvH, bdvM;
    { W4 w1; w1.u = *(const uint4*)&hbh[n][4*G]; bdvH = w1.s; }
    { W4 w2; w2.u = *(const uint4*)&hbm[n][4*G]; bdvM = w2.s; }
    __syncthreads();

    // ---------------- decoder fragments (hidden 17 padded to 32) ----------------
    short8 AwhDH[4], AwhDM[4];
    f32x4  accd[4];
    {
        short8 AihDH[4], AihDM[4];
#pragma unroll
        for (int q = 0; q < 4; ++q) {
            const int jp = 16*w + n;            // padded A-row unit
            const bool rv = (jp < 17);
            const int grow = q*17 + jp;         // real weight row (iff rv)
#pragma unroll
            for (int e = 0; e < 8; ++e) {
                const int k = 8*G + e;
                const float iv = rv ? wih_d[grow*32 + k] : 0.f;
                const float wv = (rv && k < 17) ? whh_d[grow*17 + k] : 0.f;
                const short hi = f2bfs(iv);
                AihDH[q][e] = hi;
                AihDM[q][e] = f2bfs(iv - bf2f((unsigned short)hi));
                const short hi2 = f2bfs(wv);
                AwhDH[q][e] = hi2;
                AwhDM[q][e] = f2bfs(wv - bf2f((unsigned short)hi2));
            }
#pragma unroll
            for (int r = 0; r < 4; ++r) {
                const int jq = 16*w + 4*G + r;
                accd[q][r] = (jq < 17) ? (bih_d[q*17+jq] + bhh_d[q*17+jq]) : 0.f;
            }
        }
#pragma unroll
        for (int q = 0; q < 4; ++q)
            accd[q] = __builtin_amdgcn_mfma_f32_16x16x32_bf16(AihDH[q], bdvH, accd[q], 0, 0, 0);
#pragma unroll
        for (int q = 0; q < 4; ++q)
            accd[q] = __builtin_amdgcn_mfma_f32_16x16x32_bf16(AihDM[q], bdvH, accd[q], 0, 0, 0);
#pragma unroll
        for (int q = 0; q < 4; ++q)
            accd[q] = __builtin_amdgcn_mfma_f32_16x16x32_bf16(AihDH[q], bdvM, accd[q], 0, 0, 0);
    }

    float cd[4];
#pragma unroll
    for (int s = 0; s < 4; ++s) cd[s] = 0.f;
    short8 bhdH, bhdM;
#pragma unroll
    for (int e = 0; e < 8; ++e) { bhdH[e] = 0; bhdM[e] = 0; }

    const long orow = (long)(row0 + n) * (T_STEPS * D_INP);

    // ---------------- decoder loop ----------------
    for (int t = 0; t < T_STEPS; ++t) {
        f32x4 a[4];
#pragma unroll
        for (int q = 0; q < 4; ++q) a[q] = accd[q];
#pragma unroll
        for (int q = 0; q < 4; ++q)
            a[q] = __builtin_amdgcn_mfma_f32_16x16x32_bf16(AwhDH[q], bhdH, a[q], 0, 0, 0);
#pragma unroll
        for (int q = 0; q < 4; ++q)
            a[q] = __builtin_amdgcn_mfma_f32_16x16x32_bf16(AwhDM[q], bhdH, a[q], 0, 0, 0);
#pragma unroll
        for (int q = 0; q < 4; ++q)
            a[q] = __builtin_amdgcn_mfma_f32_16x16x32_bf16(AwhDH[q], bhdM, a[q], 0, 0, 0);

        float hval[4];
        unsigned short huH[4], huM[4];
#pragma unroll
        for (int r = 0; r < 4; ++r) {
            const float cn = fsig(a[1][r])*cd[r] + fsig(a[0][r])*ftanh(a[2][r]);
            cd[r] = cn;
            const float hn = fsig(a[3][r])*ftanh(cn);
            hval[r] = hn;
            huH[r] = f2bf(hn);
            huM[r] = f2bf(hn - bf2f(huH[r]));
        }

        *(uint2*)&hbh[n][8*w + 2*G] = make_uint2((unsigned)huH[0] | ((unsigned)huH[1]<<16),
                                                 (unsigned)huH[2] | ((unsigned)huH[3]<<16));
        *(uint2*)&hbm[n][8*w + 2*G] = make_uint2((unsigned)huM[0] | ((unsigned)huM[1]<<16),
                                                 (unsigned)huM[2] | ((unsigned)huM[3]<<16));
        __syncthreads();
        { W4 w1; w1.u = *(const uint4*)&hbh[n][4*G]; bhdH = w1.s; }
        { W4 w2; w2.u = *(const uint4*)&hbm[n][4*G]; bhdM = w2.s; }
        __syncthreads();

        const long ob = orow + (long)t*D_INP;
        if (w == 0) {
#pragma unroll
            for (int r = 0; r < 4; ++r)
                out[ob + 4*G + r] = hval[r];
        } else if (G == 0) {
            out[ob + 16] = hval[0];
        }
    }
}

extern "C" void kernel_launch(void* const* d_in, const int* in_sizes, int n_in,
                              void* d_out, int out_size, void* d_ws, size_t ws_size,
                              hipStream_t stream) {
    (void)in_sizes; (void)n_in; (void)d_ws; (void)ws_size; (void)out_size;
    dim3 grid(B_TOT / 16);
    dim3 block(128);
    hipLaunchKernelGGL(lstm_ae_mfma2, grid, block, 0, stream,
        (const float*)d_in[0],
        (const float*)d_in[1],
        (const float*)d_in[2],
        (const float*)d_in[3],
        (const float*)d_in[4],
        (const float*)d_in[5],
        (const float*)d_in[6],
        (const float*)d_in[7],
        (const float*)d_in[8],
        (const float*)d_in[9],
        (const float*)d_in[10],
        (const float*)d_in[11],
        (const float*)d_in[12],
        (float*)d_out);
}

// Round 9
// 486.155 us; speedup vs baseline: 4.4320x; 1.1045x over previous
//
#include <hip/hip_runtime.h>

typedef float f32x4 __attribute__((ext_vector_type(4)));
typedef short short8 __attribute__((ext_vector_type(8)));

#define B_TOT   8192
#define T_STEPS 256
#define D_INP   17
#define OUT0 ((long)B_TOT * T_STEPS * D_INP)

__device__ __forceinline__ float bf2f(unsigned short u) {
    union { unsigned int i; float f; } v; v.i = ((unsigned int)u) << 16; return v.f;
}
__device__ __forceinline__ unsigned short f2bf(float x) {
    union { float f; unsigned int i; } v; v.f = x;
    unsigned int r = (v.i + 0x7fffu + ((v.i >> 16) & 1u)) >> 16;
    return (unsigned short)r;
}
__device__ __forceinline__ short f2bfs(float x) { return (short)f2bf(x); }

__device__ __forceinline__ float fsig(float x) {
    float t = __builtin_amdgcn_exp2f(-1.4426950408889634f * x);
    return __builtin_amdgcn_rcpf(1.0f + t);
}
__device__ __forceinline__ float ftanh(float x) {
    float t = __builtin_amdgcn_exp2f(-2.8853900817779268f * x);
    return 2.0f * __builtin_amdgcn_rcpf(1.0f + t) - 1.0f;
}

union W4 { uint4 u; short8 s; };

// 2 waves per 16-row batch tile; wave w owns hidden units [16w, 16w+16).
// h recurrence: plain bf16 exchange (no split); x prefetch depth 2.
__global__ __launch_bounds__(128, 1)
void lstm_ae_mfma3(const float* __restrict__ x,
                   const float* __restrict__ wih_e,
                   const float* __restrict__ whh_e,
                   const float* __restrict__ bih_e,
                   const float* __restrict__ bhh_e,
                   const float* __restrict__ w_encfc,
                   const float* __restrict__ b_encfc,
                   const float* __restrict__ w_decfc,
                   const float* __restrict__ b_decfc,
                   const float* __restrict__ wih_d,
                   const float* __restrict__ whh_d,
                   const float* __restrict__ bih_d,
                   const float* __restrict__ bhh_d,
                   float* __restrict__ out)
{
    const int tid  = threadIdx.x;
    const int w    = tid >> 6;     // wave id: unit half
    const int lane = tid & 63;
    const int n    = lane & 15;    // batch row within tile (C/D col)
    const int G    = lane >> 4;    // k-group / C/D row group
    const int row0 = blockIdx.x * 16;

    __shared__ unsigned int hbh[16][20];   // hi bf16 h exchange
    __shared__ unsigned int hbm[16][20];   // mid bf16 (one-time dec_in prep only)
    __shared__ float hfin[16][33];
    __shared__ float zbuf[16][8];

    // ---------------- encoder fragments (gate q = i,f,g,o) ----------------
    short8 AihH[4], AwhH[4];
    f32x4  biasE[4];
#pragma unroll
    for (int q = 0; q < 4; ++q) {
        const int grow = 32*q + 16*w + n;       // gate row
#pragma unroll
        for (int e = 0; e < 8; ++e) {
            const int k = 8*G + e;
            AwhH[q][e] = f2bfs(whh_e[grow*32 + k]);
            AihH[q][e] = (k < D_INP) ? f2bfs(wih_e[grow*D_INP + k]) : (short)0;
        }
#pragma unroll
        for (int r = 0; r < 4; ++r) {
            const int g = 32*q + 16*w + 4*G + r;
            biasE[q][r] = bih_e[g] + bhh_e[g];
        }
    }

    float c[4], h[4];
#pragma unroll
    for (int s = 0; s < 4; ++s) { c[s] = 0.f; h[s] = 0.f; }

    short8 bhH;
#pragma unroll
    for (int e = 0; e < 8; ++e) bhH[e] = 0;

    const long xrow = (long)(row0 + n) * (T_STEPS * D_INP);

    // depth-2 x prefetch: xv = x[t], xn1 = x[t+1]
    float xv[8], xn1[8];
#pragma unroll
    for (int e = 0; e < 8; ++e) {
        const int k = 8*G + e;
        xv[e]  = (k < D_INP) ? x[xrow + k] : 0.f;
        xn1[e] = (k < D_INP) ? x[xrow + D_INP + k] : 0.f;
    }

    // ---------------- encoder loop ----------------
    for (int t = 0; t < T_STEPS; ++t) {
        const int t2 = (t+2 < T_STEPS) ? (t+2) : (T_STEPS-1);
        float xn2[8];
#pragma unroll
        for (int e = 0; e < 8; ++e) {
            const int k = 8*G + e;
            xn2[e] = (k < D_INP) ? x[xrow + (long)t2*D_INP + k] : 0.f;
        }

        short8 bx;
#pragma unroll
        for (int e = 0; e < 8; ++e) bx[e] = f2bfs(xv[e]);

        f32x4 a[4];
#pragma unroll
        for (int q = 0; q < 4; ++q) a[q] = biasE[q];
#pragma unroll
        for (int q = 0; q < 4; ++q)
            a[q] = __builtin_amdgcn_mfma_f32_16x16x32_bf16(AihH[q], bx, a[q], 0, 0, 0);
#pragma unroll
        for (int q = 0; q < 4; ++q)
            a[q] = __builtin_amdgcn_mfma_f32_16x16x32_bf16(AwhH[q], bhH, a[q], 0, 0, 0);

        unsigned short huH[4];
#pragma unroll
        for (int r = 0; r < 4; ++r) {
            const float cn = fsig(a[1][r])*c[r] + fsig(a[0][r])*ftanh(a[2][r]);
            c[r] = cn;
            const float hn = fsig(a[3][r])*ftanh(cn);
            h[r] = hn;
            huH[r] = f2bf(hn);
        }

        *(uint2*)&hbh[n][8*w + 2*G] = make_uint2((unsigned)huH[0] | ((unsigned)huH[1]<<16),
                                                 (unsigned)huH[2] | ((unsigned)huH[3]<<16));
        __syncthreads();
        { W4 w1; w1.u = *(const uint4*)&hbh[n][4*G]; bhH = w1.s; }
        __syncthreads();

#pragma unroll
        for (int e = 0; e < 8; ++e) { xv[e] = xn1[e]; xn1[e] = xn2[e]; }
    }

    // ---------------- enc_fc -> z -> dec_fc ----------------
#pragma unroll
    for (int r = 0; r < 4; ++r)
        hfin[n][16*w + 4*G + r] = h[r];
    __syncthreads();

    {   // one (row nn, z-dim p) per thread: 16*8 = 128
        const int nn = tid >> 3;
        const int p  = tid & 7;
        float s = b_encfc[p];
#pragma unroll
        for (int j = 0; j < 32; ++j)
            s += hfin[nn][j] * w_encfc[p*32 + j];
        out[OUT0 + (long)(row0+nn)*8 + p] = s;
        zbuf[nn][p] = s;
    }
    __syncthreads();

    // dec_in (16 rows x 32 dims): hi+mid split (one-time, feeds accd precompute)
#pragma unroll
    for (int it = 0; it < 2; ++it) {
        const int i  = tid + 128*it;       // word index 0..255
        const int nn = i >> 4;
        const int wq = i & 15;
        unsigned short vh[2], vm[2];
#pragma unroll
        for (int half = 0; half < 2; ++half) {
            const int q = 2*wq + half;
            float v = b_decfc[q];
#pragma unroll
            for (int p = 0; p < 8; ++p)
                v += zbuf[nn][p] * w_decfc[q*8 + p];
            vh[half] = f2bf(v);
            vm[half] = f2bf(v - bf2f(vh[half]));
        }
        hbh[nn][wq] = (unsigned)vh[0] | ((unsigned)vh[1] << 16);
        hbm[nn][wq] = (unsigned)vm[0] | ((unsigned)vm[1] << 16);
    }
    __syncthreads();
    short8 bdvH, bdvM;
    { W4 w1; w1.u = *(const uint4*)&hbh[n][4*G]; bdvH = w1.s; }
    { W4 w2; w2.u = *(const uint4*)&hbm[n][4*G]; bdvM = w2.s; }
    __syncthreads();

    // ---------------- decoder fragments (hidden 17 padded to 32) ----------------
    short8 AwhDH[4];
    f32x4  accd[4];
    {
        short8 AihDH[4], AihDM[4];
#pragma unroll
        for (int q = 0; q < 4; ++q) {
            const int jp = 16*w + n;            // padded A-row unit
            const bool rv = (jp < 17);
            const int grow = q*17 + jp;         // real weight row (iff rv)
#pragma unroll
            for (int e = 0; e < 8; ++e) {
                const int k = 8*G + e;
                const float iv = rv ? wih_d[grow*32 + k] : 0.f;
                const float wv = (rv && k < 17) ? whh_d[grow*17 + k] : 0.f;
                const short hi = f2bfs(iv);
                AihDH[q][e] = hi;
                AihDM[q][e] = f2bfs(iv - bf2f((unsigned short)hi));
                AwhDH[q][e] = f2bfs(wv);
            }
#pragma unroll
            for (int r = 0; r < 4; ++r) {
                const int jq = 16*w + 4*G + r;
                accd[q][r] = (jq < 17) ? (bih_d[q*17+jq] + bhh_d[q*17+jq]) : 0.f;
            }
        }
#pragma unroll
        for (int q = 0; q < 4; ++q)
            accd[q] = __builtin_amdgcn_mfma_f32_16x16x32_bf16(AihDH[q], bdvH, accd[q], 0, 0, 0);
#pragma unroll
        for (int q = 0; q < 4; ++q)
            accd[q] = __builtin_amdgcn_mfma_f32_16x16x32_bf16(AihDM[q], bdvH, accd[q], 0, 0, 0);
#pragma unroll
        for (int q = 0; q < 4; ++q)
            accd[q] = __builtin_amdgcn_mfma_f32_16x16x32_bf16(AihDH[q], bdvM, accd[q], 0, 0, 0);
    }

    float cd[4];
#pragma unroll
    for (int s = 0; s < 4; ++s) cd[s] = 0.f;
    short8 bhdH;
#pragma unroll
    for (int e = 0; e < 8; ++e) bhdH[e] = 0;

    const long orow = (long)(row0 + n) * (T_STEPS * D_INP);

    // ---------------- decoder loop ----------------
    for (int t = 0; t < T_STEPS; ++t) {
        f32x4 a[4];
#pragma unroll
        for (int q = 0; q < 4; ++q) a[q] = accd[q];
#pragma unroll
        for (int q = 0; q < 4; ++q)
            a[q] = __builtin_amdgcn_mfma_f32_16x16x32_bf16(AwhDH[q], bhdH, a[q], 0, 0, 0);

        float hval[4];
        unsigned short huH[4];
#pragma unroll
        for (int r = 0; r < 4; ++r) {
            const float cn = fsig(a[1][r])*cd[r] + fsig(a[0][r])*ftanh(a[2][r]);
            cd[r] = cn;
            const float hn = fsig(a[3][r])*ftanh(cn);
            hval[r] = hn;
            huH[r] = f2bf(hn);
        }

        *(uint2*)&hbh[n][8*w + 2*G] = make_uint2((unsigned)huH[0] | ((unsigned)huH[1]<<16),
                                                 (unsigned)huH[2] | ((unsigned)huH[3]<<16));
        __syncthreads();
        { W4 w1; w1.u = *(const uint4*)&hbh[n][4*G]; bhdH = w1.s; }
        __syncthreads();

        const long ob = orow + (long)t*D_INP;
        if (w == 0) {
#pragma unroll
            for (int r = 0; r < 4; ++r)
                out[ob + 4*G + r] = hval[r];
        } else if (G == 0) {
            out[ob + 16] = hval[0];
        }
    }
}

extern "C" void kernel_launch(void* const* d_in, const int* in_sizes, int n_in,
                              void* d_out, int out_size, void* d_ws, size_t ws_size,
                              hipStream_t stream) {
    (void)in_sizes; (void)n_in; (void)d_ws; (void)ws_size; (void)out_size;
    dim3 grid(B_TOT / 16);
    dim3 block(128);
    hipLaunchKernelGGL(lstm_ae_mfma3, grid, block, 0, stream,
        (const float*)d_in[0],
        (const float*)d_in[1],
        (const float*)d_in[2],
        (const float*)d_in[3],
        (const float*)d_in[4],
        (const float*)d_in[5],
        (const float*)d_in[6],
        (const float*)d_in[7],
        (const float*)d_in[8],
        (const float*)d_in[9],
        (const float*)d_in[10],
        (const float*)d_in[11],
        (const float*)d_in[12],
        (float*)d_out);
}

// Round 10
// 441.033 us; speedup vs baseline: 4.8854x; 1.1023x over previous
//
#include <hip/hip_runtime.h>

typedef float f32x4 __attribute__((ext_vector_type(4)));
typedef short short8 __attribute__((ext_vector_type(8)));

#define B_TOT   8192
#define T_STEPS 256
#define D_INP   17
#define OUT0 ((long)B_TOT * T_STEPS * D_INP)

__device__ __forceinline__ float bf2f(unsigned short u) {
    union { unsigned int i; float f; } v; v.i = ((unsigned int)u) << 16; return v.f;
}
__device__ __forceinline__ unsigned short f2bf(float x) {
    union { float f; unsigned int i; } v; v.f = x;
    unsigned int r = (v.i + 0x7fffu + ((v.i >> 16) & 1u)) >> 16;
    return (unsigned short)r;
}
__device__ __forceinline__ short f2bfs(float x) { return (short)f2bf(x); }

__device__ __forceinline__ float fsig(float x) {
    float t = __builtin_amdgcn_exp2f(-1.4426950408889634f * x);
    return __builtin_amdgcn_rcpf(1.0f + t);
}
__device__ __forceinline__ float ftanh(float x) {
    float t = __builtin_amdgcn_exp2f(-2.8853900817779268f * x);
    return 2.0f * __builtin_amdgcn_rcpf(1.0f + t) - 1.0f;
}

// Single wave per 16-row batch tile. Gate-row permutation P(i)=32q+8(i>>2)+4j+(i&3)
// makes each lane's C/D output exactly its own next-step B-fragment:
// lane (n,G), acc (q,j,r)  <->  gate q of unit u=8G+4j+r, batch n.
// => recurrence has NO LDS, NO barriers, NO cross-lane ops.
__global__ __launch_bounds__(64, 1)
void lstm_ae_mfma4(const float* __restrict__ x,
                   const float* __restrict__ wih_e,
                   const float* __restrict__ whh_e,
                   const float* __restrict__ bih_e,
                   const float* __restrict__ bhh_e,
                   const float* __restrict__ w_encfc,
                   const float* __restrict__ b_encfc,
                   const float* __restrict__ w_decfc,
                   const float* __restrict__ b_decfc,
                   const float* __restrict__ wih_d,
                   const float* __restrict__ whh_d,
                   const float* __restrict__ bih_d,
                   const float* __restrict__ bhh_d,
                   float* __restrict__ out)
{
    const int lane = threadIdx.x;
    const int n    = lane & 15;    // batch row within tile (A-row / B-col / C-col)
    const int G    = lane >> 4;    // k-group / C-row group
    const int row0 = blockIdx.x * 16;

    __shared__ float hfin[16][33];
    __shared__ float zbuf[16][8];

    // ---------------- encoder fragments, permuted gate rows ----------------
    short8 Aih[4][2], Awh[4][2];
    f32x4  biasE[4][2];
#pragma unroll
    for (int q = 0; q < 4; ++q) {
#pragma unroll
        for (int j = 0; j < 2; ++j) {
            const int u0   = 8*(n>>2) + 4*j + (n&3);   // A-row unit for this lane
            const int grow = 32*q + u0;
#pragma unroll
            for (int e = 0; e < 8; ++e) {
                const int k = 8*G + e;
                Awh[q][j][e] = f2bfs(whh_e[grow*32 + k]);
                Aih[q][j][e] = (k < D_INP) ? f2bfs(wih_e[grow*D_INP + k]) : (short)0;
            }
#pragma unroll
            for (int r = 0; r < 4; ++r) {
                const int u = 8*G + 4*j + r;           // C-slot unit for this lane
                biasE[q][j][r] = bih_e[32*q + u] + bhh_e[32*q + u];
            }
        }
    }

    float c[8], hreg[8];
#pragma unroll
    for (int e = 0; e < 8; ++e) { c[e] = 0.f; hreg[e] = 0.f; }
    short8 bh;
#pragma unroll
    for (int e = 0; e < 8; ++e) bh[e] = 0;

    const long xrow = (long)(row0 + n) * (T_STEPS * D_INP);

    float xv[8];
#pragma unroll
    for (int e = 0; e < 8; ++e) {
        const int k = 8*G + e;
        xv[e] = (k < D_INP) ? x[xrow + k] : 0.f;
    }

    // ---------------- encoder loop (no LDS, no barriers) ----------------
    for (int t = 0; t < T_STEPS; ++t) {
        const int tn = (t+1 < T_STEPS) ? (t+1) : t;
        float xn[8];
#pragma unroll
        for (int e = 0; e < 8; ++e) {
            const int k = 8*G + e;
            xn[e] = (k < D_INP) ? x[xrow + (long)tn*D_INP + k] : 0.f;
        }

        short8 bx;
#pragma unroll
        for (int e = 0; e < 8; ++e) bx[e] = f2bfs(xv[e]);

        f32x4 a[4][2];
#pragma unroll
        for (int q = 0; q < 4; ++q)
#pragma unroll
            for (int j = 0; j < 2; ++j)
                a[q][j] = __builtin_amdgcn_mfma_f32_16x16x32_bf16(Aih[q][j], bx, biasE[q][j], 0, 0, 0);
#pragma unroll
        for (int q = 0; q < 4; ++q)
#pragma unroll
            for (int j = 0; j < 2; ++j)
                a[q][j] = __builtin_amdgcn_mfma_f32_16x16x32_bf16(Awh[q][j], bh, a[q][j], 0, 0, 0);

#pragma unroll
        for (int j = 0; j < 2; ++j)
#pragma unroll
            for (int r = 0; r < 4; ++r) {
                const int e = 4*j + r;
                const float cn = fsig(a[1][j][r])*c[e] + fsig(a[0][j][r])*ftanh(a[2][j][r]);
                c[e] = cn;
                const float hn = fsig(a[3][j][r])*ftanh(cn);
                hreg[e] = hn;
                bh[e] = f2bfs(hn);
            }

#pragma unroll
        for (int e = 0; e < 8; ++e) xv[e] = xn[e];
    }

    // ---------------- enc_fc -> z -> dec_fc (one-time glue) ----------------
#pragma unroll
    for (int j = 0; j < 2; ++j)
#pragma unroll
        for (int r = 0; r < 4; ++r)
            hfin[n][8*G + 4*j + r] = hreg[4*j + r];
    __syncthreads();

#pragma unroll
    for (int ti = 0; ti < 2; ++ti) {
        const int tk = lane*2 + ti;
        const int nn = tk >> 3;
        const int p  = tk & 7;
        float s = b_encfc[p];
#pragma unroll
        for (int jj = 0; jj < 32; ++jj)
            s += hfin[nn][jj] * w_encfc[p*32 + jj];
        out[OUT0 + (long)(row0+nn)*8 + p] = s;
        zbuf[nn][p] = s;
    }
    __syncthreads();

    // dec_in B-fragment directly per lane (hi+mid split, one-time)
    short8 bdvH, bdvM;
#pragma unroll
    for (int e = 0; e < 8; ++e) {
        const int k = 8*G + e;
        float v = b_decfc[k];
#pragma unroll
        for (int p = 0; p < 8; ++p)
            v += zbuf[n][p] * w_decfc[k*8 + p];
        const unsigned short hh = f2bf(v);
        bdvH[e] = (short)hh;
        bdvM[e] = f2bfs(v - bf2f(hh));
    }

    // ---------------- decoder fragments (hidden 17 padded to 32) ----------------
    short8 AwhD[4][2];
    f32x4  accd[4][2];
#pragma unroll
    for (int q = 0; q < 4; ++q) {
#pragma unroll
        for (int j = 0; j < 2; ++j) {
            const int u0   = 8*(n>>2) + 4*j + (n&3);
            const bool rv  = (u0 < 17);
            const int grow = q*17 + u0;
            short8 ADH, ADM;
#pragma unroll
            for (int e = 0; e < 8; ++e) {
                const int k = 8*G + e;
                const float iv = rv ? wih_d[grow*32 + k] : 0.f;
                const float wv = (rv && k < 17) ? whh_d[grow*17 + k] : 0.f;
                const short hi = f2bfs(iv);
                ADH[e] = hi;
                ADM[e] = f2bfs(iv - bf2f((unsigned short)hi));
                AwhD[q][j][e] = f2bfs(wv);
            }
            f32x4 acc0;
#pragma unroll
            for (int r = 0; r < 4; ++r) {
                const int u = 8*G + 4*j + r;
                acc0[r] = (u < 17) ? (bih_d[q*17 + u] + bhh_d[q*17 + u]) : 0.f;
            }
            acc0 = __builtin_amdgcn_mfma_f32_16x16x32_bf16(ADH, bdvH, acc0, 0, 0, 0);
            acc0 = __builtin_amdgcn_mfma_f32_16x16x32_bf16(ADM, bdvH, acc0, 0, 0, 0);
            acc0 = __builtin_amdgcn_mfma_f32_16x16x32_bf16(ADH, bdvM, acc0, 0, 0, 0);
            accd[q][j] = acc0;
        }
    }

    float cd[8];
#pragma unroll
    for (int e = 0; e < 8; ++e) cd[e] = 0.f;
    short8 bhd;
#pragma unroll
    for (int e = 0; e < 8; ++e) bhd[e] = 0;

    const long orow = (long)(row0 + n) * (T_STEPS * D_INP);

    // ---------------- decoder loop (no LDS, no barriers) ----------------
    for (int t = 0; t < T_STEPS; ++t) {
        f32x4 a[4][2];
#pragma unroll
        for (int q = 0; q < 4; ++q)
#pragma unroll
            for (int j = 0; j < 2; ++j)
                a[q][j] = __builtin_amdgcn_mfma_f32_16x16x32_bf16(AwhD[q][j], bhd, accd[q][j], 0, 0, 0);

        const long ob = orow + (long)t * D_INP;
#pragma unroll
        for (int j = 0; j < 2; ++j)
#pragma unroll
            for (int r = 0; r < 4; ++r) {
                const int e = 4*j + r;
                const float cn = fsig(a[1][j][r])*cd[e] + fsig(a[0][j][r])*ftanh(a[2][j][r]);
                cd[e] = cn;
                const float hn = fsig(a[3][j][r])*ftanh(cn);
                bhd[e] = f2bfs(hn);
                const int u = 8*G + 4*j + r;
                if (u < D_INP)
                    out[ob + u] = hn;
            }
    }
}

extern "C" void kernel_launch(void* const* d_in, const int* in_sizes, int n_in,
                              void* d_out, int out_size, void* d_ws, size_t ws_size,
                              hipStream_t stream) {
    (void)in_sizes; (void)n_in; (void)d_ws; (void)ws_size; (void)out_size;
    dim3 grid(B_TOT / 16);
    dim3 block(64);
    hipLaunchKernelGGL(lstm_ae_mfma4, grid, block, 0, stream,
        (const float*)d_in[0],
        (const float*)d_in[1],
        (const float*)d_in[2],
        (const float*)d_in[3],
        (const float*)d_in[4],
        (const float*)d_in[5],
        (const float*)d_in[6],
        (const float*)d_in[7],
        (const float*)d_in[8],
        (const float*)d_in[9],
        (const float*)d_in[10],
        (const float*)d_in[11],
        (const float*)d_in[12],
        (float*)d_out);
}